// Round 3
// baseline (251.030 us; speedup 1.0000x reference)
//
#include <hip/hip_runtime.h>
#include <math.h>

typedef unsigned short u16;
typedef __bf16 bf16x8 __attribute__((ext_vector_type(8)));
typedef float f32x4 __attribute__((ext_vector_type(4)));
typedef unsigned short u16x8 __attribute__((ext_vector_type(8)));

static __device__ __forceinline__ u16 f2bf(float f) {
  unsigned int u = __builtin_bit_cast(unsigned int, f);
  u = (u + 0x7FFFu + ((u >> 16) & 1u)) >> 16;
  return (u16)u;
}
static __device__ __forceinline__ float bf2f(u16 u) {
  unsigned int x = ((unsigned int)u) << 16;
  return __builtin_bit_cast(float, x);
}

// ---------------- f32 -> (hi, lo) bf16 split ----------------
__global__ __launch_bounds__(256) void cvt_split(const float* __restrict__ src, u16* __restrict__ hi,
                                                 u16* __restrict__ lo, int n4) {
  int idx = blockIdx.x * 256 + threadIdx.x;
  if (idx < n4) {
    float4 v = ((const float4*)src)[idx];
    ushort4 h, l;
    h.x = f2bf(v.x); l.x = f2bf(v.x - bf2f(h.x));
    h.y = f2bf(v.y); l.y = f2bf(v.y - bf2f(h.y));
    h.z = f2bf(v.z); l.z = f2bf(v.z - bf2f(h.z));
    h.w = f2bf(v.w); l.w = f2bf(v.w - bf2f(h.w));
    ((ushort4*)hi)[idx] = h;
    ((ushort4*)lo)[idx] = l;
  }
}

// ---------------- split-bf16 NT GEMM: C = (Ah+Al) * (Bh+Bl)^T, f32 out ----------------
// 128x128 tile, BK=32, 256 threads (4 waves, each 64x64). 3-term MFMA (drop Al*Bl).
__global__ __launch_bounds__(256) void gemm_split(const u16* __restrict__ Ah, const u16* __restrict__ Al,
                                                  const u16* __restrict__ Bh, const u16* __restrict__ Bl,
                                                  float* __restrict__ C, int M, int N, int K) {
  __shared__ __align__(16) u16 sAh[128][40];
  __shared__ __align__(16) u16 sAl[128][40];
  __shared__ __align__(16) u16 sBh[128][40];
  __shared__ __align__(16) u16 sBl[128][40];
  const int tid = threadIdx.x;
  const int w = tid >> 6, lane = tid & 63;
  const int m0 = blockIdx.x * 128, n0 = blockIdx.y * 128;
  const int wm = (w >> 1) * 64, wn = (w & 1) * 64;

  f32x4 acc[4][4] = {};

  const int srw = tid >> 1, sc0 = (tid & 1) * 16;

  for (int k0 = 0; k0 < K; k0 += 32) {
    {
      const u16* pa  = Ah + (size_t)(m0 + srw) * K + k0 + sc0;
      const u16* pal = Al + (size_t)(m0 + srw) * K + k0 + sc0;
      const u16* pb  = Bh + (size_t)(n0 + srw) * K + k0 + sc0;
      const u16* pbl = Bl + (size_t)(n0 + srw) * K + k0 + sc0;
      *(u16x8*)&sAh[srw][sc0]     = *(const u16x8*)pa;
      *(u16x8*)&sAh[srw][sc0 + 8] = *(const u16x8*)(pa + 8);
      *(u16x8*)&sAl[srw][sc0]     = *(const u16x8*)pal;
      *(u16x8*)&sAl[srw][sc0 + 8] = *(const u16x8*)(pal + 8);
      *(u16x8*)&sBh[srw][sc0]     = *(const u16x8*)pb;
      *(u16x8*)&sBh[srw][sc0 + 8] = *(const u16x8*)(pb + 8);
      *(u16x8*)&sBl[srw][sc0]     = *(const u16x8*)pbl;
      *(u16x8*)&sBl[srw][sc0 + 8] = *(const u16x8*)(pbl + 8);
    }
    __syncthreads();
    bf16x8 ah[4], al[4], bh_[4], bl[4];
#pragma unroll
    for (int m = 0; m < 4; ++m) {
      const int r = wm + m * 16 + (lane & 15);
      const int c = (lane >> 4) * 8;
      ah[m] = *(const bf16x8*)&sAh[r][c];
      al[m] = *(const bf16x8*)&sAl[r][c];
    }
#pragma unroll
    for (int n = 0; n < 4; ++n) {
      const int r = wn + n * 16 + (lane & 15);
      const int c = (lane >> 4) * 8;
      bh_[n] = *(const bf16x8*)&sBh[r][c];
      bl[n]  = *(const bf16x8*)&sBl[r][c];
    }
#pragma unroll
    for (int m = 0; m < 4; ++m)
#pragma unroll
      for (int n = 0; n < 4; ++n) {
        f32x4 a = acc[m][n];
        a = __builtin_amdgcn_mfma_f32_16x16x32_bf16(ah[m], bh_[n], a, 0, 0, 0);
        a = __builtin_amdgcn_mfma_f32_16x16x32_bf16(ah[m], bl[n], a, 0, 0, 0);
        a = __builtin_amdgcn_mfma_f32_16x16x32_bf16(al[m], bh_[n], a, 0, 0, 0);
        acc[m][n] = a;
      }
    __syncthreads();
  }

#pragma unroll
  for (int m = 0; m < 4; ++m) {
#pragma unroll
    for (int i = 0; i < 4; ++i) {
      int gr = m0 + wm + m * 16 + (lane >> 4) * 4 + i;
      float* crow = C + (size_t)gr * N + n0 + wn + (lane & 15);
#pragma unroll
      for (int n = 0; n < 4; ++n) crow[n * 16] = acc[m][n][i];
    }
  }
}

// ---------------- RMSNorm + RoPE + V cast + gate ----------------
__global__ __launch_bounds__(256) void norm_rope_gate(const float* __restrict__ qkv, const float* __restrict__ x,
                                                      const float* __restrict__ qw, const float* __restrict__ kw,
                                                      const float* __restrict__ gw,
                                                      u16* __restrict__ Q, u16* __restrict__ Kd,
                                                      u16* __restrict__ V, float* __restrict__ gate) {
  const int t = blockIdx.x * 4 + (threadIdx.x >> 6);
  const int lane = threadIdx.x & 63;
  const int b = t >> 11, s = t & 2047;
  const float* base = qkv + (size_t)t * 1536;
  const int ri = lane >> 1;
  float sn, cs;
  sincosf((float)s * expf(-(float)ri * (9.21034037198f / 32.0f)), &sn, &cs);
  const float qwl = qw[lane], kwl = kw[lane];

  for (int hh = 0; hh < 16; ++hh) {
    float v = base[hh * 64 + lane];
    float ss = v * v;
#pragma unroll
    for (int off = 32; off >= 1; off >>= 1) ss += __shfl_xor(ss, off);
    float r = rsqrtf(ss * (1.0f / 64.0f) + 1.1920929e-7f);
    float xn = v * r * qwl;
    float p = __shfl_xor(xn, 1);
    // interleaved RoPE: even out = x0*cos - x1*sin ; odd out = x1*cos + x0*sin
    // own value (xn) always gets cos; partner (p) gets sin, sign by parity.
    float outv = ((lane & 1) == 0) ? (xn * cs - p * sn) : (xn * cs + p * sn);
    Q[((size_t)(b * 16 + hh) * 2048 + s) * 64 + lane] = f2bf(outv);
  }
  for (int hh = 0; hh < 4; ++hh) {
    float v = base[1024 + hh * 64 + lane];
    float ss = v * v;
#pragma unroll
    for (int off = 32; off >= 1; off >>= 1) ss += __shfl_xor(ss, off);
    float r = rsqrtf(ss * (1.0f / 64.0f) + 1.1920929e-7f);
    float xn = v * r * kwl;
    float p = __shfl_xor(xn, 1);
    float outv = ((lane & 1) == 0) ? (xn * cs - p * sn) : (xn * cs + p * sn);
    Kd[((size_t)(b * 4 + hh) * 2048 + s) * 64 + lane] = f2bf(outv);
    V[((size_t)(b * 4 + hh) * 2048 + s) * 64 + lane] = f2bf(base[1280 + hh * 64 + lane]);
  }
  if (lane < 16) {
    float g = 0.f;
#pragma unroll
    for (int j = 0; j < 12; ++j) g += x[(size_t)t * 1024 + j] * gw[lane * 12 + j];
    gate[(size_t)t * 16 + lane] = 1.0f / (1.0f + __expf(-g));
  }
}

// ---------------- V transpose: [bh][s][d] -> [bh][d][s] ----------------
__global__ __launch_bounds__(256) void transpose_v64(const u16* __restrict__ V, u16* __restrict__ Vt) {
  __shared__ __align__(16) u16 tile[64][72];
  const int st = blockIdx.x, bh = blockIdx.y;
  const u16* src = V + ((size_t)bh * 2048 + st * 64) * 64;
  u16* dst = Vt + (size_t)bh * 64 * 2048 + st * 64;
  const int t = threadIdx.x;
  const int r = t >> 2, c0 = (t & 3) * 16;
#pragma unroll
  for (int j = 0; j < 2; ++j)
    *(u16x8*)&tile[r][c0 + j * 8] = *(const u16x8*)&src[(size_t)r * 64 + c0 + j * 8];
  __syncthreads();
  u16 tmp[16];
#pragma unroll
  for (int j = 0; j < 16; ++j) tmp[j] = tile[c0 + j][r];
#pragma unroll
  for (int j = 0; j < 2; ++j)
    *(u16x8*)&dst[(size_t)r * 2048 + c0 + j * 8] = *(const u16x8*)&tmp[j * 8];
}

// ---------------- Flash attention, causal GQA ----------------
// grid (S/64, B*H); 4 waves; wave w owns q rows [q0+16w, q0+16w+16)
__global__ __launch_bounds__(256) void attn_fwd(const u16* __restrict__ Q, const u16* __restrict__ Kg,
                                                const u16* __restrict__ Vt, const float* __restrict__ gate,
                                                u16* __restrict__ attnh, u16* __restrict__ attnl) {
  __shared__ __align__(16) u16 sK[64][72];   // K[kv][d]
  __shared__ __align__(16) u16 sV[64][72];   // Vt[d][kv]
  __shared__ __align__(16) u16 sP[4][16][72];

  const int tid = threadIdx.x;
  const int w = tid >> 6, lane = tid & 63;
  const int qi = blockIdx.x;
  const int q0 = qi * 64;
  const int bh = blockIdx.y;
  const int b = bh >> 4, h = bh & 15;
  const int kvh = h >> 2;

  const u16* Qp = Q + (size_t)(b * 16 + h) * 2048 * 64;
  const u16* Kp = Kg + (size_t)(b * 4 + kvh) * 2048 * 64;
  const u16* Vp = Vt + (size_t)(b * 4 + kvh) * 64 * 2048;

  bf16x8 qa[2];
  {
    const u16* qrow = Qp + (size_t)(q0 + w * 16 + (lane & 15)) * 64 + (lane >> 4) * 8;
    qa[0] = *(const bf16x8*)qrow;
    qa[1] = *(const bf16x8*)(qrow + 32);
  }

  f32x4 acc[4] = {};
  float m_run[4], l_run[4];
#pragma unroll
  for (int i = 0; i < 4; ++i) { m_run[i] = -1e30f; l_run[i] = 0.f; }

  const int srw = tid >> 2, sc0 = (tid & 3) * 16;

  for (int t = 0; t <= qi; ++t) {
    const int kv0 = t * 64;
    {
      const u16* kg = Kp + (size_t)(kv0 + srw) * 64 + sc0;
      const u16* vg = Vp + (size_t)srw * 2048 + kv0 + sc0;
      *(u16x8*)&sK[srw][sc0]     = *(const u16x8*)kg;
      *(u16x8*)&sK[srw][sc0 + 8] = *(const u16x8*)(kg + 8);
      *(u16x8*)&sV[srw][sc0]     = *(const u16x8*)vg;
      *(u16x8*)&sV[srw][sc0 + 8] = *(const u16x8*)(vg + 8);
    }
    __syncthreads();

    // S = Q K^T  (16 x 64 per wave)
    f32x4 sc[4];
#pragma unroll
    for (int ct = 0; ct < 4; ++ct) {
      f32x4 s4 = {};
      const int r = ct * 16 + (lane & 15);
#pragma unroll
      for (int kt = 0; kt < 2; ++kt) {
        bf16x8 kb = *(const bf16x8*)&sK[r][kt * 32 + (lane >> 4) * 8];
        s4 = __builtin_amdgcn_mfma_f32_16x16x32_bf16(qa[kt], kb, s4, 0, 0, 0);
      }
      sc[ct] = s4;
    }

    // online softmax (rows live across the 16-lane group lane&15)
    float pmax[4] = {-1e30f, -1e30f, -1e30f, -1e30f};
    const int colb = kv0 + (lane & 15);
    const int rowb = q0 + w * 16 + (lane >> 4) * 4;
#pragma unroll
    for (int ct = 0; ct < 4; ++ct)
#pragma unroll
      for (int i = 0; i < 4; ++i) {
        float v = sc[ct][i] * 0.125f;
        v = (colb + ct * 16 <= rowb + i) ? v : -1e30f;
        sc[ct][i] = v;
        pmax[i] = fmaxf(pmax[i], v);
      }
#pragma unroll
    for (int off = 8; off >= 1; off >>= 1)
#pragma unroll
      for (int i = 0; i < 4; ++i) pmax[i] = fmaxf(pmax[i], __shfl_xor(pmax[i], off));

    float alpha[4], rsum[4];
#pragma unroll
    for (int i = 0; i < 4; ++i) {
      float mn = fmaxf(m_run[i], pmax[i]);
      alpha[i] = __expf(m_run[i] - mn);
      m_run[i] = mn;
      rsum[i] = 0.f;
    }
    // P in bf16; accumulate denominator from the ROUNDED values for consistency
    u16 pb[4][4];
#pragma unroll
    for (int ct = 0; ct < 4; ++ct)
#pragma unroll
      for (int i = 0; i < 4; ++i) {
        float p = __expf(sc[ct][i] - m_run[i]);
        u16 pbits = f2bf(p);
        pb[ct][i] = pbits;
        rsum[i] += bf2f(pbits);
      }
#pragma unroll
    for (int off = 8; off >= 1; off >>= 1)
#pragma unroll
      for (int i = 0; i < 4; ++i) rsum[i] += __shfl_xor(rsum[i], off);
#pragma unroll
    for (int i = 0; i < 4; ++i) l_run[i] = l_run[i] * alpha[i] + rsum[i];
#pragma unroll
    for (int n = 0; n < 4; ++n)
#pragma unroll
      for (int i = 0; i < 4; ++i) acc[n][i] *= alpha[i];

    // P -> LDS (per-wave region)
#pragma unroll
    for (int ct = 0; ct < 4; ++ct)
#pragma unroll
      for (int i = 0; i < 4; ++i)
        sP[w][(lane >> 4) * 4 + i][ct * 16 + (lane & 15)] = pb[ct][i];

    __syncthreads();

    bf16x8 pa[2];
    pa[0] = *(const bf16x8*)&sP[w][lane & 15][(lane >> 4) * 8];
    pa[1] = *(const bf16x8*)&sP[w][lane & 15][32 + (lane >> 4) * 8];
#pragma unroll
    for (int n = 0; n < 4; ++n) {
      const int r = n * 16 + (lane & 15);
#pragma unroll
      for (int kt = 0; kt < 2; ++kt) {
        bf16x8 vb = *(const bf16x8*)&sV[r][kt * 32 + (lane >> 4) * 8];
        acc[n] = __builtin_amdgcn_mfma_f32_16x16x32_bf16(pa[kt], vb, acc[n], 0, 0, 0);
      }
    }
    __syncthreads();
  }

  // epilogue: O = acc / l * gate, split-write hi/lo bf16 [token][h*64+d]
#pragma unroll
  for (int i = 0; i < 4; ++i) {
    int srowg = q0 + w * 16 + (lane >> 4) * 4 + i;
    float g = gate[((size_t)b * 2048 + srowg) * 16 + h];
    float inv = 1.0f / l_run[i];
    size_t rowoff = ((size_t)b * 2048 + srowg) * 1024 + h * 64 + (lane & 15);
    u16* oh = attnh + rowoff;
    u16* ol = attnl + rowoff;
#pragma unroll
    for (int n = 0; n < 4; ++n) {
      float o = acc[n][i] * inv * g;
      u16 hbits = f2bf(o);
      oh[n * 16] = hbits;
      ol[n * 16] = f2bf(o - bf2f(hbits));
    }
  }
}

// ---------------- launch ----------------
extern "C" void kernel_launch(void* const* d_in, const int* in_sizes, int n_in,
                              void* d_out, int out_size, void* d_ws, size_t ws_size,
                              hipStream_t stream) {
  const float* x  = (const float*)d_in[0];
  const float* Wf = (const float*)d_in[1];
  const float* qw = (const float*)d_in[2];
  const float* kw = (const float*)d_in[3];
  const float* gw = (const float*)d_in[4];
  float* out = (float*)d_out;

  char* ws = (char*)d_ws;
  size_t off = 0;
  auto alloc = [&](size_t bytes) { void* p = ws + off; off += (bytes + 255) & ~(size_t)255; return p; };

  u16*   xh   = (u16*)alloc((size_t)4096 * 1024 * 2);
  u16*   xl   = (u16*)alloc((size_t)4096 * 1024 * 2);
  u16*   wh   = (u16*)alloc((size_t)2560 * 1024 * 2);
  u16*   wl   = (u16*)alloc((size_t)2560 * 1024 * 2);
  float* qkv  = (float*)alloc((size_t)4096 * 1536 * 4);
  u16*   Qb   = (u16*)alloc((size_t)2 * 16 * 2048 * 64 * 2);
  u16*   Kb   = (u16*)alloc((size_t)2 * 4 * 2048 * 64 * 2);
  u16*   Vb   = (u16*)alloc((size_t)2 * 4 * 2048 * 64 * 2);
  u16*   Vtb  = (u16*)alloc((size_t)2 * 4 * 2048 * 64 * 2);
  float* gate = (float*)alloc((size_t)2 * 2048 * 16 * 4);
  // attn hi/lo alias x hi/lo (dead after the QKV GEMM)
  u16*   attnh = xh;
  u16*   attnl = xl;

  cvt_split<<<dim3(4096), dim3(256), 0, stream>>>(x, xh, xl, 4096 * 1024 / 4);
  cvt_split<<<dim3(2560), dim3(256), 0, stream>>>(Wf, wh, wl, 2560 * 1024 / 4);
  gemm_split<<<dim3(32, 12), dim3(256), 0, stream>>>(xh, xl, wh, wl, qkv, 4096, 1536, 1024);
  norm_rope_gate<<<dim3(1024), dim3(256), 0, stream>>>(qkv, x, qw, kw, gw, Qb, Kb, Vb, gate);
  transpose_v64<<<dim3(32, 8), dim3(256), 0, stream>>>(Vb, Vtb);
  attn_fwd<<<dim3(32, 32), dim3(256), 0, stream>>>(Qb, Kb, Vtb, gate, attnh, attnl);
  gemm_split<<<dim3(32, 8), dim3(256), 0, stream>>>(attnh, attnl, wh + (size_t)1536 * 1024, wl + (size_t)1536 * 1024,
                                                    out, 4096, 1024, 1024);
}